// Round 1
// baseline (683.340 us; speedup 1.0000x reference)
//
#include <hip/hip_runtime.h>

// Fused: out = ((1-t)*v0*warp(frame0,f0) + t*v1*warp(frame1,f1)) / ((1-t)*v0 + (t*v1 + 1e-12))
// TFA dense_image_warp semantics: q = grid - flow; floor clamped to [0, size-2]; alphas clamped [0,1].
//
// Shapes fixed by the problem: B=8, H=720, W=1280, C=3.
// Memory-bound: ~442 MB ideal HBM traffic -> ~70 us floor at 6.3 TB/s.
// 4 pixels/thread along j so flows (float4 x2), v (float4), out (float4 x3) are vectorized;
// bilinear gathers stay scalar and rely on L1/L2 spatial locality (flow ~ N(0,1)).

namespace {

constexpr int B = 8, H = 720, W = 1280;
constexpr int HW = H * W;
constexpr int TOTAL = B * HW;       // 7,372,800
constexpr int PPT = 4;              // pixels per thread (W % 4 == 0 -> no row crossing)
constexpr int BLOCK = 256;

__device__ __forceinline__ void bilinear3(const float* __restrict__ img,
                                          float qy, float qx, float out3[3]) {
    float fy = fminf(fmaxf(floorf(qy), 0.0f), (float)(H - 2));
    float fx = fminf(fmaxf(floorf(qx), 0.0f), (float)(W - 2));
    float ay = fminf(fmaxf(qy - fy, 0.0f), 1.0f);
    float ax = fminf(fmaxf(qx - fx, 0.0f), 1.0f);
    int iy = (int)fy;
    int ix = (int)fx;
    const float* p0 = img + ((size_t)iy * W + ix) * 3;  // top-left pixel
    const float* p1 = p0 + (size_t)W * 3;               // bottom-left pixel
#pragma unroll
    for (int c = 0; c < 3; ++c) {
        float tl = p0[c], tr = p0[c + 3];
        float bl = p1[c], br = p1[c + 3];
        float top = tl + ax * (tr - tl);
        float bot = bl + ax * (br - bl);
        out3[c] = top + ay * (bot - top);
    }
}

__global__ __launch_bounds__(BLOCK) void warp_blend_kernel(
    const float* __restrict__ fr0, const float* __restrict__ ft0,
    const float* __restrict__ v0p, const float* __restrict__ fr1,
    const float* __restrict__ ft1, const float* __restrict__ v1p,
    const float* __restrict__ tp, float* __restrict__ out) {
    int g = blockIdx.x * BLOCK + threadIdx.x;
    int pix0 = g * PPT;
    if (pix0 >= TOTAL) return;

    const float t = tp[0];
    const float omt = 1.0f - t;

    int b = pix0 / HW;
    int rem = pix0 - b * HW;
    int i = rem / W;
    int j = rem - i * W;  // j .. j+3 in the same row

    // Vectorized streaming loads (all 16B-aligned since pix0 % 4 == 0).
    float4 f0a = *reinterpret_cast<const float4*>(ft0 + (size_t)pix0 * 2);
    float4 f0b = *reinterpret_cast<const float4*>(ft0 + (size_t)pix0 * 2 + 4);
    float4 f1a = *reinterpret_cast<const float4*>(ft1 + (size_t)pix0 * 2);
    float4 f1b = *reinterpret_cast<const float4*>(ft1 + (size_t)pix0 * 2 + 4);
    float4 v0 = *reinterpret_cast<const float4*>(v0p + (size_t)pix0);
    float4 v1 = *reinterpret_cast<const float4*>(v1p + (size_t)pix0);

    const float fl0y[4] = {f0a.x, f0a.z, f0b.x, f0b.z};
    const float fl0x[4] = {f0a.y, f0a.w, f0b.y, f0b.w};
    const float fl1y[4] = {f1a.x, f1a.z, f1b.x, f1b.z};
    const float fl1x[4] = {f1a.y, f1a.w, f1b.y, f1b.w};
    const float vv0[4] = {v0.x, v0.y, v0.z, v0.w};
    const float vv1[4] = {v1.x, v1.y, v1.z, v1.w};

    const float* img0 = fr0 + (size_t)b * HW * 3;
    const float* img1 = fr1 + (size_t)b * HW * 3;

    float res[12];
#pragma unroll
    for (int p = 0; p < 4; ++p) {  // fully unrolled -> all array indexing compile-time (no scratch)
        float w0c[3], w1c[3];
        bilinear3(img0, (float)i - fl0y[p], (float)(j + p) - fl0x[p], w0c);
        bilinear3(img1, (float)i - fl1y[p], (float)(j + p) - fl1x[p], w1c);
        float a0 = omt * vv0[p];
        float a1 = t * vv1[p];
        float z = a0 + (a1 + 1e-12f);
        float inv = 1.0f / z;  // one IEEE divide, then 3 muls (<=2 ulp vs per-channel divide)
#pragma unroll
        for (int c = 0; c < 3; ++c)
            res[p * 3 + c] = (a0 * w0c[c] + a1 * w1c[c]) * inv;
    }

    // 48B contiguous store per thread, 16B-aligned (pix0*3 floats, pix0 % 4 == 0).
    float4* ov = reinterpret_cast<float4*>(out + (size_t)pix0 * 3);
    ov[0] = make_float4(res[0], res[1], res[2], res[3]);
    ov[1] = make_float4(res[4], res[5], res[6], res[7]);
    ov[2] = make_float4(res[8], res[9], res[10], res[11]);
}

}  // namespace

extern "C" void kernel_launch(void* const* d_in, const int* in_sizes, int n_in,
                              void* d_out, int out_size, void* d_ws, size_t ws_size,
                              hipStream_t stream) {
    const float* fr0 = (const float*)d_in[0];
    const float* ft0 = (const float*)d_in[1];
    const float* v0  = (const float*)d_in[2];
    const float* fr1 = (const float*)d_in[3];
    const float* ft1 = (const float*)d_in[4];
    const float* v1  = (const float*)d_in[5];
    const float* tp  = (const float*)d_in[6];
    float* out = (float*)d_out;

    constexpr int groups = TOTAL / PPT;     // 1,843,200
    constexpr int blocks = groups / BLOCK;  // 7,200 exactly
    warp_blend_kernel<<<blocks, BLOCK, 0, stream>>>(fr0, ft0, v0, fr1, ft1, v1, tp, out);
}

// Round 3
// 427.926 us; speedup vs baseline: 1.5969x; 1.5969x over previous
//
#include <hip/hip_runtime.h>

// Fused: out = ((1-t)*v0*warp(frame0,f0) + t*v1*warp(frame1,f1)) / ((1-t)*v0 + (t*v1 + 1e-12))
// TFA dense_image_warp semantics: q = grid - flow; floor clamped to [0, size-2]; alphas clamped [0,1].
//
// B=8, H=720, W=1280, C=3. Ideal HBM traffic ~442 MB -> ~70 us floor at 6.3 TB/s.
// R1 found 4.9x read amplification (1.68 GB fetched): linear blockIdx round-robins
// neighboring blocks across the 8 non-coherent per-XCD L2s, so every XCD re-fetched
// the same frame rows. Fix: XCD-chunked swizzle (each XCD gets one contiguous batch)
// + non-temporal access for the single-use streams (flows, v, out) to keep L2 for
// the gathered frame lines.
// (R2 bench was an infra failure — container died; identical kernel resubmitted.)

namespace {

constexpr int B = 8, H = 720, W = 1280;
constexpr int HW = H * W;
constexpr int TOTAL = B * HW;       // 7,372,800
constexpr int PPT = 4;              // pixels per thread (W % 4 == 0 -> no row crossing)
constexpr int BLOCK = 256;
constexpr int NBLOCKS = TOTAL / PPT / BLOCK;  // 7200, divisible by 8
constexpr int NXCD = 8;

using f32x4 = __attribute__((ext_vector_type(4))) float;

__device__ __forceinline__ void bilinear3(const float* __restrict__ img,
                                          float qy, float qx, float out3[3]) {
    float fy = fminf(fmaxf(floorf(qy), 0.0f), (float)(H - 2));
    float fx = fminf(fmaxf(floorf(qx), 0.0f), (float)(W - 2));
    float ay = fminf(fmaxf(qy - fy, 0.0f), 1.0f);
    float ax = fminf(fmaxf(qx - fx, 0.0f), 1.0f);
    int iy = (int)fy;
    int ix = (int)fx;
    const float* p0 = img + ((size_t)iy * W + ix) * 3;  // top-left pixel
    const float* p1 = p0 + (size_t)W * 3;               // bottom-left pixel
#pragma unroll
    for (int c = 0; c < 3; ++c) {
        float tl = p0[c], tr = p0[c + 3];
        float bl = p1[c], br = p1[c + 3];
        float top = tl + ax * (tr - tl);
        float bot = bl + ax * (br - bl);
        out3[c] = top + ay * (bot - top);
    }
}

__global__ __launch_bounds__(BLOCK) void warp_blend_kernel(
    const float* __restrict__ fr0, const float* __restrict__ ft0,
    const float* __restrict__ v0p, const float* __restrict__ fr1,
    const float* __restrict__ ft1, const float* __restrict__ v1p,
    const float* __restrict__ tp, float* __restrict__ out) {
    // XCD-chunked swizzle: HW round-robins blockIdx across 8 XCDs; remap so XCD k
    // processes the contiguous logical range [k*NBLOCKS/8, (k+1)*NBLOCKS/8) — here
    // exactly one batch image per XCD, so all gather reuse is within one L2.
    int bid = (blockIdx.x % NXCD) * (NBLOCKS / NXCD) + blockIdx.x / NXCD;
    int g = bid * BLOCK + threadIdx.x;
    int pix0 = g * PPT;

    const float t = tp[0];
    const float omt = 1.0f - t;

    int b = pix0 / HW;
    int rem = pix0 - b * HW;
    int i = rem / W;
    int j = rem - i * W;  // j .. j+3 in the same row

    // Single-use streams: non-temporal so they don't evict frame lines from L2.
    f32x4 f0a = __builtin_nontemporal_load((const f32x4*)(ft0 + (size_t)pix0 * 2));
    f32x4 f0b = __builtin_nontemporal_load((const f32x4*)(ft0 + (size_t)pix0 * 2) + 1);
    f32x4 f1a = __builtin_nontemporal_load((const f32x4*)(ft1 + (size_t)pix0 * 2));
    f32x4 f1b = __builtin_nontemporal_load((const f32x4*)(ft1 + (size_t)pix0 * 2) + 1);
    f32x4 v0 = __builtin_nontemporal_load((const f32x4*)(v0p + (size_t)pix0));
    f32x4 v1 = __builtin_nontemporal_load((const f32x4*)(v1p + (size_t)pix0));

    const float fl0y[4] = {f0a.x, f0a.z, f0b.x, f0b.z};
    const float fl0x[4] = {f0a.y, f0a.w, f0b.y, f0b.w};
    const float fl1y[4] = {f1a.x, f1a.z, f1b.x, f1b.z};
    const float fl1x[4] = {f1a.y, f1a.w, f1b.y, f1b.w};
    const float vv0[4] = {v0.x, v0.y, v0.z, v0.w};
    const float vv1[4] = {v1.x, v1.y, v1.z, v1.w};

    const float* img0 = fr0 + (size_t)b * HW * 3;
    const float* img1 = fr1 + (size_t)b * HW * 3;

    float res[12];
#pragma unroll
    for (int p = 0; p < 4; ++p) {  // fully unrolled -> compile-time indexing (no scratch)
        float w0c[3], w1c[3];
        bilinear3(img0, (float)i - fl0y[p], (float)(j + p) - fl0x[p], w0c);
        bilinear3(img1, (float)i - fl1y[p], (float)(j + p) - fl1x[p], w1c);
        float a0 = omt * vv0[p];
        float a1 = t * vv1[p];
        float z = a0 + (a1 + 1e-12f);
        float inv = 1.0f / z;  // one IEEE divide, then 3 muls (<=2 ulp vs per-channel divide)
#pragma unroll
        for (int c = 0; c < 3; ++c)
            res[p * 3 + c] = (a0 * w0c[c] + a1 * w1c[c]) * inv;
    }

    // 48B contiguous store per thread, 16B-aligned; non-temporal (write-once stream).
    f32x4* ov = (f32x4*)(out + (size_t)pix0 * 3);
    f32x4 o0 = {res[0], res[1], res[2], res[3]};
    f32x4 o1 = {res[4], res[5], res[6], res[7]};
    f32x4 o2 = {res[8], res[9], res[10], res[11]};
    __builtin_nontemporal_store(o0, ov + 0);
    __builtin_nontemporal_store(o1, ov + 1);
    __builtin_nontemporal_store(o2, ov + 2);
}

}  // namespace

extern "C" void kernel_launch(void* const* d_in, const int* in_sizes, int n_in,
                              void* d_out, int out_size, void* d_ws, size_t ws_size,
                              hipStream_t stream) {
    const float* fr0 = (const float*)d_in[0];
    const float* ft0 = (const float*)d_in[1];
    const float* v0  = (const float*)d_in[2];
    const float* fr1 = (const float*)d_in[3];
    const float* ft1 = (const float*)d_in[4];
    const float* v1  = (const float*)d_in[5];
    const float* tp  = (const float*)d_in[6];
    float* out = (float*)d_out;

    warp_blend_kernel<<<NBLOCKS, BLOCK, 0, stream>>>(fr0, ft0, v0, fr1, ft1, v1, tp, out);
}